// Round 6
// baseline (556.380 us; speedup 1.0000x reference)
//
#include <hip/hip_runtime.h>
#include <hip/hip_bf16.h>

typedef __hip_bfloat16 bf16;
typedef __attribute__((ext_vector_type(8))) short bf16x8;
typedef __attribute__((ext_vector_type(4))) float f32x4;

#define CEMB 384
#define NHEAD 6
#define HSZ 64
#define TSEQ 256
#define BATCH 128
#define MROWS (BATCH*TSEQ)   // 32768
#define FDIM 1536
#define QSCALE 0.05103103630798288f  // 384^-0.5
#define SMAX 8.0f                    // static softmax max (scores bounded ~|2.5|)

#define AS1 __attribute__((address_space(1)))
#define AS3 __attribute__((address_space(3)))
// async global->LDS, 16B/lane: LDS dest = wave-uniform base + lane*16 (HW rule)
__device__ __forceinline__ void gload16(const void* g, void* l){
  __builtin_amdgcn_global_load_lds((const AS1 unsigned*)(g), (AS3 unsigned*)(l), 16, 0, 0);
}

// ---------------- LayerNorm: fp32 in -> bf16 out (one wave per row) ----------------
__global__ __launch_bounds__(256) void ln_kernel(const float* __restrict__ x,
    const float* __restrict__ gam, const float* __restrict__ bet,
    bf16* __restrict__ y)
{
  const int row  = blockIdx.x*4 + (threadIdx.x>>6);
  const int lane = threadIdx.x & 63;
  const float* xr = x + (size_t)row*CEMB;
  float v[6]; float s = 0.f;
  #pragma unroll
  for (int i=0;i<6;i++){ v[i] = xr[lane + i*64]; s += v[i]; }
  #pragma unroll
  for (int m=1;m<64;m<<=1) s += __shfl_xor(s, m, 64);
  const float mu = s * (1.0f/CEMB);
  float qs = 0.f;
  #pragma unroll
  for (int i=0;i<6;i++){ v[i] -= mu; qs += v[i]*v[i]; }
  #pragma unroll
  for (int m=1;m<64;m<<=1) qs += __shfl_xor(qs, m, 64);
  const float rs = rsqrtf(qs*(1.0f/CEMB) + 1e-5f);
  bf16* yr = y + (size_t)row*CEMB;
  #pragma unroll
  for (int i=0;i<6;i++){
    int c = lane + i*64;
    yr[c] = __float2bfloat16(v[i]*rs*gam[c] + bet[c]);
  }
}

// ---------------- Weight transpose + fp32->bf16 ----------------
// src: (G, K, N) fp32 row-major  ->  dst: (G, N, K) bf16 row-major
__global__ __launch_bounds__(256) void transpose_to_bf16(const float* __restrict__ src,
    bf16* __restrict__ dst, int K, int N)
{
  __shared__ float tile[32][33];
  const int n0 = blockIdx.x*32, k0 = blockIdx.y*32;
  src += (size_t)blockIdx.z*K*N;
  dst += (size_t)blockIdx.z*K*N;
  const int c = threadIdx.x & 31, r8 = threadIdx.x >> 5;
  #pragma unroll
  for (int i=0;i<4;i++)
    tile[r8 + i*8][c] = src[(size_t)(k0 + r8 + i*8)*N + n0 + c];
  __syncthreads();
  #pragma unroll
  for (int i=0;i<4;i++)
    dst[(size_t)(n0 + r8 + i*8)*K + k0 + c] = __float2bfloat16(tile[c][r8 + i*8]);
}

// Merged q/k/v weight transpose: z = src_sel*6 + head; each (384,64) -> (64,384)
__global__ __launch_bounds__(256) void transpose_qkv(const float* __restrict__ Wq,
    const float* __restrict__ Wk, const float* __restrict__ Wv, bf16* __restrict__ dst)
{
  __shared__ float tile[32][33];
  const int z = blockIdx.z;
  const float* src = (z < 6) ? Wq : (z < 12 ? Wk : Wv);
  src += (size_t)(z % 6) * CEMB * HSZ;
  dst += (size_t)z * CEMB * HSZ;
  const int n0 = blockIdx.x*32, k0 = blockIdx.y*32;
  const int c = threadIdx.x & 31, r8 = threadIdx.x >> 5;
  #pragma unroll
  for (int i=0;i<4;i++)
    tile[r8 + i*8][c] = src[(size_t)(k0 + r8 + i*8)*HSZ + n0 + c];
  __syncthreads();
  #pragma unroll
  for (int i=0;i<4;i++)
    dst[(size_t)(n0 + r8 + i*8)*CEMB + k0 + c] = __float2bfloat16(tile[c][r8 + i*8]);
}

// ---------------- strip GEMM: C[M,N] = A[M,K] @ BT[N,K]^T, A-strip resident in LDS ----
// Shape rationale: K is small (384 per chunk) and weights BT are tiny (<=1.2MB,
// L2-resident). Each block owns a 64-row A strip, stages it ONCE into 48KB LDS
// (gload16, one barrier), then loops over all N tiles reading B fragments DIRECTLY
// from global (L2 hits) -> ZERO barriers in the compute loops; waves free-run.
// 4 waves (2M x 2N): wave tile 32 x 64; inner group = 3 N-tiles of 128 (acc[3][2][4]).
// KC>1 (FF2, K=1536): A staged in KC chunks of 384, acc carried across chunks.
// LDS swizzle: 16B-block' = block ^ (row&7) -> balanced 8-access/bank ds_read_b128;
// realized by pre-swizzling the GLOBAL source block (rule #21).
// EPI: 0 = QKV scatter (q scaled; q,k,v (b,h,t,d)), 1/3 = +bias+resid -> f32,
//      2 = relu(+bias) -> bf16
template<int EPI, int NTO, int KC>
__global__ __launch_bounds__(256) void strip_gemm(
    const bf16* __restrict__ A, const bf16* __restrict__ BT,
    const float* __restrict__ bias, const float* __restrict__ resid,
    float* __restrict__ outf, bf16* __restrict__ outb0,
    bf16* __restrict__ outb1, bf16* __restrict__ outb2)
{
  constexpr int NTI = 3;
  constexpr int N   = NTO*NTI*128;          // total output cols
  constexpr size_t ROWB = (size_t)KC*768;   // bytes per row of A and BT (K*2)
  __shared__ char ldsA[64*768];             // 48 KB A-chunk [64 rows][48 x 16B blocks]
  const int bm = blockIdx.x*64;
  const int t = threadIdx.x, lane = t & 63, wid = t >> 6;
  const int wr = (wid>>1)*32, wc = (wid&1)*64;
  const int g = lane >> 4, fr = lane & 15;

  auto stage = [&](int kc){
    #pragma unroll
    for (int i=0;i<12;i++){
      int idx = i*256 + t;                  // 16B-slot 0..3071
      int row = idx/48, blk = idx - row*48;
      gload16((const char*)A + (size_t)(bm+row)*ROWB + kc*768 + ((blk ^ (row&7))<<4),
              ldsA + idx*16);
    }
  };

  if constexpr (KC==1){ stage(0); __syncthreads(); }

  #pragma unroll 1
  for (int nto=0; nto<NTO; ++nto){
    f32x4 acc[NTI][2][4] = {};
    #pragma unroll 1
    for (int kc=0; kc<KC; ++kc){
      if constexpr (KC>1){
        if (kc) __syncthreads();            // prev chunk reads done
        stage(kc);
        __syncthreads();
      }
      #pragma unroll
      for (int ks=0; ks<12; ++ks){
        bf16x8 af[2];
        #pragma unroll
        for (int mi=0;mi<2;mi++){
          int row = wr + mi*16 + fr;
          af[mi] = *(const bf16x8*)(ldsA + row*768 + (((ks*4+g) ^ (row&7))<<4));
        }
        #pragma unroll
        for (int nti=0; nti<NTI; ++nti){
          bf16x8 bq[4];
          #pragma unroll
          for (int nj=0;nj<4;nj++){
            int n = (nto*NTI + nti)*128 + wc + nj*16 + fr;
            bq[nj] = *(const bf16x8*)((const char*)BT + (size_t)n*ROWB + kc*768 + ks*64 + g*16);
          }
          __builtin_amdgcn_s_setprio(1);
          #pragma unroll
          for (int mi=0;mi<2;mi++)
            #pragma unroll
            for (int nj=0;nj<4;nj++)
              acc[nti][mi][nj] = __builtin_amdgcn_mfma_f32_16x16x32_bf16(
                  af[mi], bq[nj], acc[nti][mi][nj], 0, 0, 0);
          __builtin_amdgcn_s_setprio(0);
        }
      }
    }
    // epilogue for this 384-col group: acc elem e -> (row 16mi+4g+e, col 16nj+fr)
    #pragma unroll
    for (int nti=0; nti<NTI; ++nti)
      #pragma unroll
      for (int mi=0;mi<2;mi++)
        #pragma unroll
        for (int nj=0;nj<4;nj++)
          #pragma unroll
          for (int e=0;e<4;e++){
            const int m  = bm + wr + mi*16 + 4*g + e;
            const int nn = nti*128 + wc + nj*16 + fr;   // 0..383 within group
            const float vacc = acc[nti][mi][nj][e];
            if constexpr (EPI==0){
              int hh = nn>>6, dd = nn&63;
              int bb = m>>8,  tt = m&255;
              bf16 val = __float2bfloat16(nto==0 ? vacc * QSCALE : vacc);
              bf16* dst = nto==0 ? outb0 : (nto==1 ? outb1 : outb2);
              dst[((size_t)(bb*NHEAD + hh)*TSEQ + tt)*HSZ + dd] = val;
            } else if constexpr (EPI==1 || EPI==3){
              const int n = nto*384 + nn;
              outf[(size_t)m*N + n] = vacc + bias[n] + resid[(size_t)m*N + n];
            } else {
              const int n = nto*384 + nn;
              float z = vacc + bias[n];
              outb0[(size_t)m*N + n] = __float2bfloat16(z > 0.f ? z : 0.f);
            }
          }
  }
}

// ---------------- Causal flash attention, one block per (b,h), 4 waves x 64 rows ----
// q,k,v: (b,h,t,d) bf16 (q pre-scaled); out: (b,t,h*64+d) bf16
// Static softmax max (SMAX): no max/sum reductions; l folded into PV via ones-row
// (V^T row 64 = 1.0, rows 65..79 = 0) -> l accumulates in acc frag nd=4, col 64.
__global__ __launch_bounds__(256) void attn_kernel(
    const bf16* __restrict__ q, const bf16* __restrict__ k,
    const bf16* __restrict__ v, bf16* __restrict__ out)
{
  __shared__ char kt_lds[64*128];     // K tile  [s][d] single-XOR swizzled
  __shared__ char vt_lds[80*128];     // V^T [d][s] double-XOR swizzled; rows 64..79 const
  __shared__ char p_lds[4][64*128];   // per-wave P [r][s] single-XOR swizzled
  const int bh = blockIdx.x;
  const int bidx = bh / NHEAD, hidx = bh - bidx*NHEAD;
  const int t = threadIdx.x, lane = t & 63, w = t >> 6;
  const int g = lane >> 4, fr = lane & 15;
  const int lrow = lane >> 3;
  const int scol = ((lane & 7) ^ lrow) << 4;
  const size_t base = (size_t)bh * TSEQ * HSZ;

  // constant tail rows of vt: row 64 = ones (l-fold), 65..79 = zeros
  if (t < 128){
    unsigned int ones2 = 0x3F803F80u;
    uint4 vv;
    if ((t>>3) == 0) vv = uint4{ones2, ones2, ones2, ones2};
    else             vv = uint4{0u, 0u, 0u, 0u};
    *(uint4*)(vt_lds + (64 + (t>>3))*128 + (t&7)*16) = vv;
  }

  bf16x8 qf[4][2];
  #pragma unroll
  for (int mi=0;mi<4;mi++)
    #pragma unroll
    for (int ks=0;ks<2;ks++)
      qf[mi][ks] = *(const bf16x8*)(q + base + (size_t)(w*64 + mi*16 + fr)*HSZ + ks*32 + g*8);

  f32x4 of[4][5] = {};   // nd=0..3: O accum; nd=4: col 64 holds l (ones-row fold)

  for (int j=0;j<4;j++){
    __syncthreads();
    // K tile via global_load_lds (pre-swizzled source)
    #pragma unroll
    for (int i=0;i<2;i++){
      int r0 = w*16 + i*8;
      gload16((const char*)(k + base + (size_t)(j*64 + r0 + lrow)*HSZ) + scol,
              kt_lds + r0*128);
    }
    // V tile: read (t,d) coalesced, write transposed [d][s], double-XOR swizzle
    // byte = d*128 + (((s>>3) ^ (d&7) ^ ((d>>3)&7))<<4) + (s&7)*2  -> 2-way banks (free)
    #pragma unroll
    for (int i=0;i<2;i++){
      int chunk = t + i*256, r = chunk>>3, c = chunk&7;
      uint4 vv = *(const uint4*)(v + base + (size_t)(j*64 + r)*HSZ + c*8);
      const unsigned short* pv = (const unsigned short*)&vv;
      #pragma unroll
      for (int u=0;u<8;u++)
        *(unsigned short*)(vt_lds + (c*8+u)*128 + ((((r>>3) ^ u ^ c)&7)<<4) + (r&7)*2) = pv[u];
    }
    __syncthreads();
    if (j <= w){
      f32x4 sa[4][4] = {};
      #pragma unroll
      for (int ks=0;ks<2;ks++){
        bf16x8 kf[4];
        #pragma unroll
        for (int nj=0;nj<4;nj++)
          kf[nj] = *(const bf16x8*)(kt_lds + (nj*16+fr)*128 + (((ks*4+g)*16) ^ ((fr&7)<<4)));
        __builtin_amdgcn_s_setprio(1);
        #pragma unroll
        for (int mi=0;mi<4;mi++)
          #pragma unroll
          for (int nj=0;nj<4;nj++)
            sa[mi][nj] = __builtin_amdgcn_mfma_f32_16x16x32_bf16(qf[mi][ks], kf[nj], sa[mi][nj], 0, 0, 0);
        __builtin_amdgcn_s_setprio(0);
      }
      if (j == w){
        #pragma unroll
        for (int mi=0;mi<4;mi++)
          #pragma unroll
          for (int nj=0;nj<4;nj++)
            #pragma unroll
            for (int e=0;e<4;e++)
              if (nj*16 + fr > mi*16 + 4*g + e) sa[mi][nj][e] = -1e30f;
      }
      // P = exp(s - SMAX), straight to LDS (no reductions, no rescale)
      char* pl = p_lds[w];
      #pragma unroll
      for (int mi=0;mi<4;mi++)
        #pragma unroll
        for (int nj=0;nj<4;nj++)
          #pragma unroll
          for (int e=0;e<4;e++){
            int row = mi*16 + 4*g + e, col = nj*16 + fr;
            float p = __expf(sa[mi][nj][e] - SMAX);
            *(bf16*)(pl + row*128 + (((col>>3) ^ (row&7))<<4) + (col&7)*2) =
                __float2bfloat16(p);
          }
      #pragma unroll
      for (int ks=0;ks<2;ks++){
        bf16x8 pa[4], vf[5];
        #pragma unroll
        for (int mi=0;mi<4;mi++)
          pa[mi] = *(const bf16x8*)(pl + (mi*16+fr)*128 + (((ks*4+g)*16) ^ ((fr&7)<<4)));
        #pragma unroll
        for (int nd=0;nd<5;nd++){
          int d = nd*16 + fr;
          vf[nd] = *(const bf16x8*)(vt_lds + d*128 +
                   ((((ks*4+g) ^ (d&7) ^ ((d>>3)&7))&7)<<4));
        }
        __builtin_amdgcn_s_setprio(1);
        #pragma unroll
        for (int mi=0;mi<4;mi++)
          #pragma unroll
          for (int nd=0;nd<5;nd++)
            of[mi][nd] = __builtin_amdgcn_mfma_f32_16x16x32_bf16(pa[mi], vf[nd], of[mi][nd], 0, 0, 0);
        __builtin_amdgcn_s_setprio(0);
      }
    }
  }
  // l for row (16mi+4g+e) sits in of[mi][4][e] of the fr==0 lane of this g-group
  #pragma unroll
  for (int mi=0;mi<4;mi++){
    float rl[4];
    #pragma unroll
    for (int e=0;e<4;e++){
      float l = __shfl(of[mi][4][e], (int)(lane & 48), 64);
      rl[e] = 1.0f / l;
    }
    #pragma unroll
    for (int nd=0;nd<4;nd++)
      #pragma unroll
      for (int e=0;e<4;e++){
        int row = w*64 + mi*16 + 4*g + e;
        int d = nd*16 + fr;
        out[(size_t)(bidx*TSEQ + row)*CEMB + hidx*HSZ + d] =
            __float2bfloat16(of[mi][nd][e] * rl[e]);
      }
  }
}

// ---------------- launch ----------------
extern "C" void kernel_launch(void* const* d_in, const int* in_sizes, int n_in,
                              void* d_out, int out_size, void* d_ws, size_t ws_size,
                              hipStream_t stream)
{
  const float* x     = (const float*)d_in[0];
  const float* Wq    = (const float*)d_in[1];
  const float* Wk    = (const float*)d_in[2];
  const float* Wv    = (const float*)d_in[3];
  const float* Wproj = (const float*)d_in[4];
  const float* bproj = (const float*)d_in[5];
  const float* W1    = (const float*)d_in[6];
  const float* b1    = (const float*)d_in[7];
  const float* W2    = (const float*)d_in[8];
  const float* b2    = (const float*)d_in[9];
  const float* ln1g  = (const float*)d_in[10];
  const float* ln1b  = (const float*)d_in[11];
  const float* ln2g  = (const float*)d_in[12];
  const float* ln2b  = (const float*)d_in[13];

  char* ws = (char*)d_ws;
  const size_t SA = (size_t)MROWS*CEMB*2;          // one bf16 M x C slot
  bf16* xn1    = (bf16*)(ws + 0*SA);               // LN1 out      (slot 0)
  bf16* qb     = (bf16*)(ws + 1*SA);               // q (b,h,t,d), pre-scaled
  bf16* kbuf   = (bf16*)(ws + 2*SA);               // k (b,h,t,d)
  bf16* vb     = (bf16*)(ws + 3*SA);               // v (b,h,t,d)
  bf16* attn_o = (bf16*)(ws + 0*SA);               // reuse slot 0 (xn1 dead after QKV)
  bf16* act    = (bf16*)(ws + 0*SA);               // FF1 out, slots 0-3
  bf16* hb     = (bf16*)(ws + 4*SA);               // LN2 out
  float* x1    = (float*)(ws + 5*SA);              // residual stream after attn (fp32)
  char* wb     = ws + 5*SA + (size_t)MROWS*CEMB*4;
  bf16* qkvT   = (bf16*)wb;                            // (1152, 384)
  bf16* projT  = (bf16*)(wb + (size_t)1152*384*2);     // (384, 384)
  bf16* w1T    = (bf16*)(wb + (size_t)(1152+384)*384*2);      // (1536, 384)
  bf16* w2T    = (bf16*)(wb + (size_t)(1152+384+1536)*384*2); // (384, 1536)

  dim3 blk(256);
  transpose_qkv<<<dim3(2,12,18), blk, 0, stream>>>(Wq, Wk, Wv, qkvT);
  transpose_to_bf16<<<dim3(12,12,1), blk, 0, stream>>>(Wproj, projT, CEMB, CEMB);
  transpose_to_bf16<<<dim3(48,12,1), blk, 0, stream>>>(W1,    w1T,   CEMB, FDIM);
  transpose_to_bf16<<<dim3(12,48,1), blk, 0, stream>>>(W2,    w2T,   FDIM, CEMB);

  ln_kernel<<<dim3(MROWS/4), blk, 0, stream>>>(x, ln1g, ln1b, xn1);
  strip_gemm<0,3,1><<<dim3(512), blk, 0, stream>>>(xn1, qkvT, nullptr, nullptr,
                                                   nullptr, qb, kbuf, vb);
  attn_kernel<<<dim3(768), blk, 0, stream>>>(qb, kbuf, vb, attn_o);
  strip_gemm<1,1,1><<<dim3(512), blk, 0, stream>>>(attn_o, projT, bproj, x,
                                                   x1, nullptr, nullptr, nullptr);
  ln_kernel<<<dim3(MROWS/4), blk, 0, stream>>>(x1, ln2g, ln2b, hb);
  strip_gemm<2,4,1><<<dim3(512), blk, 0, stream>>>(hb, w1T, b1, nullptr,
                                                   nullptr, act, nullptr, nullptr);
  strip_gemm<3,1,4><<<dim3(512), blk, 0, stream>>>(act, w2T, b2, x1,
                                                   (float*)d_out, nullptr, nullptr, nullptr);
}

// Round 7
// 283.835 us; speedup vs baseline: 1.9602x; 1.9602x over previous
//
#include <hip/hip_runtime.h>
#include <hip/hip_bf16.h>

typedef __hip_bfloat16 bf16;
typedef __attribute__((ext_vector_type(8))) short bf16x8;
typedef __attribute__((ext_vector_type(4))) float f32x4;

#define CEMB 384
#define NHEAD 6
#define HSZ 64
#define TSEQ 256
#define BATCH 128
#define MROWS (BATCH*TSEQ)   // 32768
#define FDIM 1536
#define QSCALE 0.05103103630798288f  // 384^-0.5
#define SMAX 8.0f                    // static softmax max (scores bounded ~|2.5|)

#define AS1 __attribute__((address_space(1)))
#define AS3 __attribute__((address_space(3)))
// async global->LDS, 16B/lane: LDS dest = wave-uniform base + lane*16 (HW rule)
__device__ __forceinline__ void gload16(const void* g, void* l){
  __builtin_amdgcn_global_load_lds((const AS1 unsigned*)(g), (AS3 unsigned*)(l), 16, 0, 0);
}

// ---------------- LayerNorm: fp32 in -> bf16 out (one wave per row) ----------------
__global__ __launch_bounds__(256) void ln_kernel(const float* __restrict__ x,
    const float* __restrict__ gam, const float* __restrict__ bet,
    bf16* __restrict__ y)
{
  const int row  = blockIdx.x*4 + (threadIdx.x>>6);
  const int lane = threadIdx.x & 63;
  const float* xr = x + (size_t)row*CEMB;
  float v[6]; float s = 0.f;
  #pragma unroll
  for (int i=0;i<6;i++){ v[i] = xr[lane + i*64]; s += v[i]; }
  #pragma unroll
  for (int m=1;m<64;m<<=1) s += __shfl_xor(s, m, 64);
  const float mu = s * (1.0f/CEMB);
  float qs = 0.f;
  #pragma unroll
  for (int i=0;i<6;i++){ v[i] -= mu; qs += v[i]*v[i]; }
  #pragma unroll
  for (int m=1;m<64;m<<=1) qs += __shfl_xor(qs, m, 64);
  const float rs = rsqrtf(qs*(1.0f/CEMB) + 1e-5f);
  bf16* yr = y + (size_t)row*CEMB;
  #pragma unroll
  for (int i=0;i<6;i++){
    int c = lane + i*64;
    yr[c] = __float2bfloat16(v[i]*rs*gam[c] + bet[c]);
  }
}

// ---------------- Weight transpose + fp32->bf16 ----------------
// src: (G, K, N) fp32 row-major  ->  dst: (G, N, K) bf16 row-major
__global__ __launch_bounds__(256) void transpose_to_bf16(const float* __restrict__ src,
    bf16* __restrict__ dst, int K, int N)
{
  __shared__ float tile[32][33];
  const int n0 = blockIdx.x*32, k0 = blockIdx.y*32;
  src += (size_t)blockIdx.z*K*N;
  dst += (size_t)blockIdx.z*K*N;
  const int c = threadIdx.x & 31, r8 = threadIdx.x >> 5;
  #pragma unroll
  for (int i=0;i<4;i++)
    tile[r8 + i*8][c] = src[(size_t)(k0 + r8 + i*8)*N + n0 + c];
  __syncthreads();
  #pragma unroll
  for (int i=0;i<4;i++)
    dst[(size_t)(n0 + r8 + i*8)*K + k0 + c] = __float2bfloat16(tile[c][r8 + i*8]);
}

// Merged q/k/v weight transpose: z = src_sel*6 + head; each (384,64) -> (64,384)
__global__ __launch_bounds__(256) void transpose_qkv(const float* __restrict__ Wq,
    const float* __restrict__ Wk, const float* __restrict__ Wv, bf16* __restrict__ dst)
{
  __shared__ float tile[32][33];
  const int z = blockIdx.z;
  const float* src = (z < 6) ? Wq : (z < 12 ? Wk : Wv);
  src += (size_t)(z % 6) * CEMB * HSZ;
  dst += (size_t)z * CEMB * HSZ;
  const int n0 = blockIdx.x*32, k0 = blockIdx.y*32;
  const int c = threadIdx.x & 31, r8 = threadIdx.x >> 5;
  #pragma unroll
  for (int i=0;i<4;i++)
    tile[r8 + i*8][c] = src[(size_t)(k0 + r8 + i*8)*HSZ + n0 + c];
  __syncthreads();
  #pragma unroll
  for (int i=0;i<4;i++)
    dst[(size_t)(n0 + r8 + i*8)*CEMB + k0 + c] = __float2bfloat16(tile[c][r8 + i*8]);
}

// ---------------- GEMM: C[M,N] = A[M,K](bf16) @ BT[N,K]^T(bf16), fused epilogues ----
// BM=BN=128, BK=64, 4 waves (2x2), 16x16x32 MFMA, gload16 staging.
// Counted-vmcnt pipeline (T4): loads for tile t+1 issued a FULL iteration before their
// wait; raw s_barrier (no vmcnt(0) drain mid-loop). Schedule per iter:
//   compute(buf[t&1]) ; s_barrier ; stage(buf[t&1], t+2) ; vmcnt(8) ; s_barrier
// vmcnt(8) = stage(t+2)'s 8 loads remain outstanding, t+1's are done.
// XCD swizzle (T1, bijective, nwg%8==0): within-XCD consecutive wgs iterate bn fastest
// -> blocks sharing an A row-panel hit the same per-XCD L2.
// LDS: [128 rows][64 cols bf16]/buf, swizzle byte^=((row&7)<<4) via pre-swizzled
// GLOBAL source column (rule #21). 64KB LDS -> 2 blocks/CU TLP.
// EPI: 0 = QKV scatter (q scaled; q,k,v (b,h,t,d)), 1/3 = +bias+resid -> f32,
//      2 = relu(+bias) -> bf16
template<int EPI, int NN>
__global__ __launch_bounds__(256) void gemm_bt(
    const bf16* __restrict__ A, const bf16* __restrict__ BT, int K,
    const float* __restrict__ bias, const float* __restrict__ resid,
    float* __restrict__ outf, bf16* __restrict__ outb0,
    bf16* __restrict__ outb1, bf16* __restrict__ outb2)
{
  __shared__ char ldsA[2][128*128];
  __shared__ char ldsB[2][128*128];
  // bijective XCD swizzle: chunk of nwg/8 consecutive wgs per XCD
  const int cpx = gridDim.x >> 3;
  const int wg  = (blockIdx.x & 7)*cpx + (blockIdx.x >> 3);
  const int bm = (wg / NN)*128, bn = (wg % NN)*128;
  const int t = threadIdx.x, lane = t & 63, wid = t >> 6;
  const int wr = (wid>>1)*64, wc = (wid&1)*64;
  const int g = lane >> 4, fr = lane & 15;
  const int N = NN*128;
  const int lrow = lane >> 3;                       // 0..7: row within 8-row chunk
  const int scol = ((lane & 7) ^ lrow) << 4;        // pre-swizzled source byte col
  f32x4 acc[4][4] = {};
  const int nk = K >> 6;
  const size_t rowK2 = (size_t)K*2;                 // row stride bytes
  const char* Ab = (const char*)A + (size_t)(bm + wid*32 + lrow)*rowK2 + scol;
  const char* Bb = (const char*)BT + (size_t)(bn + wid*32 + lrow)*rowK2 + scol;

  auto stage = [&](int buf, int kt){                // 8 loads/wave
    const size_t ko = (size_t)kt*128;               // byte col offset of this K-tile
    #pragma unroll
    for (int i=0;i<4;i++){
      gload16(Ab + (size_t)i*8*rowK2 + ko, ldsA[buf] + (wid*32 + i*8)*128);
      gload16(Bb + (size_t)i*8*rowK2 + ko, ldsB[buf] + (wid*32 + i*8)*128);
    }
  };

  stage(0, 0);
  stage(1, 1);
  asm volatile("s_waitcnt vmcnt(8)" ::: "memory");  // tile 0 landed (tile 1 in flight)
  __builtin_amdgcn_s_barrier();
  for (int kt=0; kt<nk; ++kt){
    const int cur = kt & 1;
    #pragma unroll
    for (int ks=0; ks<2; ++ks){
      bf16x8 af[4], bfrag[4];
      #pragma unroll
      for (int mi=0;mi<4;mi++)
        af[mi] = *(const bf16x8*)(ldsA[cur] + (wr+mi*16+fr)*128 + (((ks*4+g)*16) ^ ((fr&7)<<4)));
      #pragma unroll
      for (int nj=0;nj<4;nj++)
        bfrag[nj] = *(const bf16x8*)(ldsB[cur] + (wc+nj*16+fr)*128 + (((ks*4+g)*16) ^ ((fr&7)<<4)));
      __builtin_amdgcn_s_setprio(1);
      #pragma unroll
      for (int mi=0;mi<4;mi++)
        #pragma unroll
        for (int nj=0;nj<4;nj++)
          acc[mi][nj] = __builtin_amdgcn_mfma_f32_16x16x32_bf16(af[mi], bfrag[nj], acc[mi][nj], 0, 0, 0);
      __builtin_amdgcn_s_setprio(0);
    }
    __builtin_amdgcn_s_barrier();                   // all waves done reading buf[cur]
    if (kt+2 < nk) stage(cur, kt+2);                // refill the buffer just freed
    if (kt+1 < nk){
      if (kt+2 < nk) asm volatile("s_waitcnt vmcnt(8)" ::: "memory");  // t+1 done
      else           asm volatile("s_waitcnt vmcnt(0)" ::: "memory");  // last tile
      __builtin_amdgcn_s_barrier();                 // buf[t+1] ready for everyone
    }
  }
  // epilogue: acc element e -> (row = 16mi+4g+e, col = 16nj+fr)
  #pragma unroll
  for (int mi=0;mi<4;mi++)
    #pragma unroll
    for (int nj=0;nj<4;nj++)
      #pragma unroll
      for (int e=0;e<4;e++){
        const int m = bm + wr + mi*16 + 4*g + e;
        const int n = bn + wc + nj*16 + fr;
        const float vacc = acc[mi][nj][e];
        if constexpr (EPI==0){
          int sel = n/CEMB; int nn = n - sel*CEMB;
          int hh = nn>>6, dd = nn&63;
          int bb = m>>8,  tt = m&255;
          bf16 val = __float2bfloat16(sel==0 ? vacc * QSCALE : vacc);
          bf16* dst = sel==0 ? outb0 : (sel==1 ? outb1 : outb2);
          dst[((size_t)(bb*NHEAD + hh)*TSEQ + tt)*HSZ + dd] = val;
        } else if constexpr (EPI==1 || EPI==3){
          outf[(size_t)m*N + n] = vacc + bias[n] + resid[(size_t)m*N + n];
        } else {
          float z = vacc + bias[n];
          outb0[(size_t)m*N + n] = __float2bfloat16(z > 0.f ? z : 0.f);
        }
      }
}

// ---------------- Causal flash attention, one block per (b,h), 4 waves x 64 rows ----
// q,k,v: (b,h,t,d) bf16 (q pre-scaled); out: (b,t,h*64+d) bf16
// Static softmax max (SMAX): no max/sum reductions; l folded into PV via ones-row
// (V^T row 64 = 1.0, rows 65..79 = 0) -> l accumulates in acc frag nd=4, col 64.
__global__ __launch_bounds__(256) void attn_kernel(
    const bf16* __restrict__ q, const bf16* __restrict__ k,
    const bf16* __restrict__ v, bf16* __restrict__ out)
{
  __shared__ char kt_lds[64*128];     // K tile  [s][d] single-XOR swizzled
  __shared__ char vt_lds[80*128];     // V^T [d][s] double-XOR swizzled; rows 64..79 const
  __shared__ char p_lds[4][64*128];   // per-wave P [r][s] single-XOR swizzled
  const int bh = blockIdx.x;
  const int bidx = bh / NHEAD, hidx = bh - bidx*NHEAD;
  const int t = threadIdx.x, lane = t & 63, w = t >> 6;
  const int g = lane >> 4, fr = lane & 15;
  const int lrow = lane >> 3;
  const int scol = ((lane & 7) ^ lrow) << 4;
  const size_t base = (size_t)bh * TSEQ * HSZ;

  // constant tail rows of vt: row 64 = ones (l-fold), 65..79 = zeros
  if (t < 128){
    unsigned int ones2 = 0x3F803F80u;
    uint4 vv;
    if ((t>>3) == 0) vv = uint4{ones2, ones2, ones2, ones2};
    else             vv = uint4{0u, 0u, 0u, 0u};
    *(uint4*)(vt_lds + (64 + (t>>3))*128 + (t&7)*16) = vv;
  }

  bf16x8 qf[4][2];
  #pragma unroll
  for (int mi=0;mi<4;mi++)
    #pragma unroll
    for (int ks=0;ks<2;ks++)
      qf[mi][ks] = *(const bf16x8*)(q + base + (size_t)(w*64 + mi*16 + fr)*HSZ + ks*32 + g*8);

  f32x4 of[4][5] = {};   // nd=0..3: O accum; nd=4: col 64 holds l (ones-row fold)

  for (int j=0;j<4;j++){
    __syncthreads();
    // K tile via global_load_lds (pre-swizzled source)
    #pragma unroll
    for (int i=0;i<2;i++){
      int r0 = w*16 + i*8;
      gload16((const char*)(k + base + (size_t)(j*64 + r0 + lrow)*HSZ) + scol,
              kt_lds + r0*128);
    }
    // V tile: read (t,d) coalesced, write transposed [d][s], double-XOR swizzle
    // byte = d*128 + (((s>>3) ^ (d&7) ^ ((d>>3)&7))<<4) + (s&7)*2  -> 2-way banks (free)
    #pragma unroll
    for (int i=0;i<2;i++){
      int chunk = t + i*256, r = chunk>>3, c = chunk&7;
      uint4 vv = *(const uint4*)(v + base + (size_t)(j*64 + r)*HSZ + c*8);
      const unsigned short* pv = (const unsigned short*)&vv;
      #pragma unroll
      for (int u=0;u<8;u++)
        *(unsigned short*)(vt_lds + (c*8+u)*128 + ((((r>>3) ^ u ^ c)&7)<<4) + (r&7)*2) = pv[u];
    }
    __syncthreads();
    if (j <= w){
      f32x4 sa[4][4] = {};
      #pragma unroll
      for (int ks=0;ks<2;ks++){
        bf16x8 kf[4];
        #pragma unroll
        for (int nj=0;nj<4;nj++)
          kf[nj] = *(const bf16x8*)(kt_lds + (nj*16+fr)*128 + (((ks*4+g)*16) ^ ((fr&7)<<4)));
        __builtin_amdgcn_s_setprio(1);
        #pragma unroll
        for (int mi=0;mi<4;mi++)
          #pragma unroll
          for (int nj=0;nj<4;nj++)
            sa[mi][nj] = __builtin_amdgcn_mfma_f32_16x16x32_bf16(qf[mi][ks], kf[nj], sa[mi][nj], 0, 0, 0);
        __builtin_amdgcn_s_setprio(0);
      }
      if (j == w){
        #pragma unroll
        for (int mi=0;mi<4;mi++)
          #pragma unroll
          for (int nj=0;nj<4;nj++)
            #pragma unroll
            for (int e=0;e<4;e++)
              if (nj*16 + fr > mi*16 + 4*g + e) sa[mi][nj][e] = -1e30f;
      }
      // P = exp(s - SMAX), straight to LDS (no reductions, no rescale)
      char* pl = p_lds[w];
      #pragma unroll
      for (int mi=0;mi<4;mi++)
        #pragma unroll
        for (int nj=0;nj<4;nj++)
          #pragma unroll
          for (int e=0;e<4;e++){
            int row = mi*16 + 4*g + e, col = nj*16 + fr;
            float p = __expf(sa[mi][nj][e] - SMAX);
            *(bf16*)(pl + row*128 + (((col>>3) ^ (row&7))<<4) + (col&7)*2) =
                __float2bfloat16(p);
          }
      #pragma unroll
      for (int ks=0;ks<2;ks++){
        bf16x8 pa[4], vf[5];
        #pragma unroll
        for (int mi=0;mi<4;mi++)
          pa[mi] = *(const bf16x8*)(pl + (mi*16+fr)*128 + (((ks*4+g)*16) ^ ((fr&7)<<4)));
        #pragma unroll
        for (int nd=0;nd<5;nd++){
          int d = nd*16 + fr;
          vf[nd] = *(const bf16x8*)(vt_lds + d*128 +
                   ((((ks*4+g) ^ (d&7) ^ ((d>>3)&7))&7)<<4));
        }
        __builtin_amdgcn_s_setprio(1);
        #pragma unroll
        for (int mi=0;mi<4;mi++)
          #pragma unroll
          for (int nd=0;nd<5;nd++)
            of[mi][nd] = __builtin_amdgcn_mfma_f32_16x16x32_bf16(pa[mi], vf[nd], of[mi][nd], 0, 0, 0);
        __builtin_amdgcn_s_setprio(0);
      }
    }
  }
  // l for row (16mi+4g+e) sits in of[mi][4][e] of the fr==0 lane of this g-group
  #pragma unroll
  for (int mi=0;mi<4;mi++){
    float rl[4];
    #pragma unroll
    for (int e=0;e<4;e++){
      float l = __shfl(of[mi][4][e], (int)(lane & 48), 64);
      rl[e] = 1.0f / l;
    }
    #pragma unroll
    for (int nd=0;nd<4;nd++)
      #pragma unroll
      for (int e=0;e<4;e++){
        int row = w*64 + mi*16 + 4*g + e;
        int d = nd*16 + fr;
        out[(size_t)(bidx*TSEQ + row)*CEMB + hidx*HSZ + d] =
            __float2bfloat16(of[mi][nd][e] * rl[e]);
      }
  }
}

// ---------------- launch ----------------
extern "C" void kernel_launch(void* const* d_in, const int* in_sizes, int n_in,
                              void* d_out, int out_size, void* d_ws, size_t ws_size,
                              hipStream_t stream)
{
  const float* x     = (const float*)d_in[0];
  const float* Wq    = (const float*)d_in[1];
  const float* Wk    = (const float*)d_in[2];
  const float* Wv    = (const float*)d_in[3];
  const float* Wproj = (const float*)d_in[4];
  const float* bproj = (const float*)d_in[5];
  const float* W1    = (const float*)d_in[6];
  const float* b1    = (const float*)d_in[7];
  const float* W2    = (const float*)d_in[8];
  const float* b2    = (const float*)d_in[9];
  const float* ln1g  = (const float*)d_in[10];
  const float* ln1b  = (const float*)d_in[11];
  const float* ln2g  = (const float*)d_in[12];
  const float* ln2b  = (const float*)d_in[13];

  char* ws = (char*)d_ws;
  const size_t SA = (size_t)MROWS*CEMB*2;          // one bf16 M x C slot
  bf16* xn1    = (bf16*)(ws + 0*SA);               // LN1 out      (slot 0)
  bf16* qb     = (bf16*)(ws + 1*SA);               // q (b,h,t,d), pre-scaled
  bf16* kbuf   = (bf16*)(ws + 2*SA);               // k (b,h,t,d)
  bf16* vb     = (bf16*)(ws + 3*SA);               // v (b,h,t,d)
  bf16* attn_o = (bf16*)(ws + 0*SA);               // reuse slot 0 (xn1 dead after QKV)
  bf16* act    = (bf16*)(ws + 0*SA);               // FF1 out, slots 0-3
  bf16* hb     = (bf16*)(ws + 4*SA);               // LN2 out
  float* x1    = (float*)(ws + 5*SA);              // residual stream after attn (fp32)
  char* wb     = ws + 5*SA + (size_t)MROWS*CEMB*4;
  bf16* qkvT   = (bf16*)wb;                            // (1152, 384)
  bf16* projT  = (bf16*)(wb + (size_t)1152*384*2);     // (384, 384)
  bf16* w1T    = (bf16*)(wb + (size_t)(1152+384)*384*2);      // (1536, 384)
  bf16* w2T    = (bf16*)(wb + (size_t)(1152+384+1536)*384*2); // (384, 1536)

  dim3 blk(256);
  transpose_qkv<<<dim3(2,12,18), blk, 0, stream>>>(Wq, Wk, Wv, qkvT);
  transpose_to_bf16<<<dim3(12,12,1), blk, 0, stream>>>(Wproj, projT, CEMB, CEMB);
  transpose_to_bf16<<<dim3(48,12,1), blk, 0, stream>>>(W1,    w1T,   CEMB, FDIM);
  transpose_to_bf16<<<dim3(12,48,1), blk, 0, stream>>>(W2,    w2T,   FDIM, CEMB);

  ln_kernel<<<dim3(MROWS/4), blk, 0, stream>>>(x, ln1g, ln1b, xn1);
  gemm_bt<0,9><<<dim3(2304), blk, 0, stream>>>(xn1, qkvT, CEMB, nullptr, nullptr,
                                               nullptr, qb, kbuf, vb);
  attn_kernel<<<dim3(768), blk, 0, stream>>>(qb, kbuf, vb, attn_o);
  gemm_bt<1,3><<<dim3(768), blk, 0, stream>>>(attn_o, projT, CEMB, bproj, x,
                                              x1, nullptr, nullptr, nullptr);
  ln_kernel<<<dim3(MROWS/4), blk, 0, stream>>>(x1, ln2g, ln2b, hb);
  gemm_bt<2,12><<<dim3(3072), blk, 0, stream>>>(hb, w1T, CEMB, b1, nullptr,
                                                nullptr, act, nullptr, nullptr);
  gemm_bt<3,3><<<dim3(768), blk, 0, stream>>>(act, w2T, FDIM, b2, x1,
                                              (float*)d_out, nullptr, nullptr, nullptr);
}